// Round 5
// baseline (424.447 us; speedup 1.0000x reference)
//
#include <hip/hip_runtime.h>

typedef _Float16 half8 __attribute__((ext_vector_type(8)));
typedef float floatx4 __attribute__((ext_vector_type(4)));
typedef float float4v __attribute__((ext_vector_type(4)));

#define DIM   768
#define NROW  196
#define AUNITS (64 * 13 * 24 * 64)    // 16B units in A'' (fragment-tiled image)
#define TUNITS (64 * 4 * 24 * 64)     // 16B units in B'' (fragment-tiled text)
#define A_HALFS ((size_t)AUNITS * 8)
#define T_HALFS ((size_t)TUNITS * 8)
#define BJ_HALFS (24 * 4 * 64 * 8)    // 49152 halfs per j
#define CHUNK_H 8192                  // halfs per 4-K-step chunk (16 KB)

__device__ __forceinline__ void gl_lds16(const _Float16* g, _Float16* l) {
  __builtin_amdgcn_global_load_lds(
      (const __attribute__((address_space(1))) unsigned int*)g,
      (__attribute__((address_space(3))) unsigned int*)l, 16, 0, 0);
}

// ---------- repack: f32 -> f16 into MFMA-fragment-tiled layout ----------
// A''[i][tau][s][lane]{8}: lane l holds A_i[n=tau*16+(l&15)][d=s*32+(l>>4)*8..+7]
// B''[j][s][ct][lane]{8}:  lane l holds B_j[m=ct*16+(l&15)][d=s*32+(l>>4)*8..+7]
__global__ __launch_bounds__(256) void repack(const float* __restrict__ img,
                                              const float* __restrict__ txt,
                                              _Float16* __restrict__ Apk,
                                              _Float16* __restrict__ Bpk,
                                              int* __restrict__ ctr) {
  int gid = blockIdx.x * 256 + threadIdx.x;
  if (gid == 0) *ctr = 0;            // completion counter for fused CE
  const float* src;
  _Float16* dst;
  if (gid < AUNITS) {
    int l = gid & 63, g = gid >> 6;
    int s = g % 24; g /= 24;
    int tau = g % 13; int i = g / 13;
    int n = tau * 16 + (l & 15); if (n > 195) n = 195;   // dup-pad rows 196..207
    src = img + (size_t)i * 197 * 768 + (size_t)(n + 1) * 768 + s * 32 + (l >> 4) * 8;
    dst = Apk + (size_t)gid * 8;
  } else {
    int u = gid - AUNITS;
    int l = u & 63, g = u >> 6;
    int ct = g & 3; g >>= 2;
    int s = g % 24; int j = g / 24;
    int m = ct * 16 + (l & 15);
    src = txt + (size_t)j * 65 * 768 + (size_t)(m + 1) * 768 + s * 32 + (l >> 4) * 8;
    dst = Bpk + (size_t)u * 8;
  }
  float4v v0 = *(const float4v*)src;
  float4v v1 = *(const float4v*)(src + 4);
  half8 h;
  h[0] = (_Float16)v0[0]; h[1] = (_Float16)v0[1]; h[2] = (_Float16)v0[2]; h[3] = (_Float16)v0[3];
  h[4] = (_Float16)v1[0]; h[5] = (_Float16)v1[1]; h[6] = (_Float16)v1[2]; h[7] = (_Float16)v1[3];
  *(half8*)dst = h;
}

// ---------- per-(i,j): A streamed via registers, B double-buffered DMA chunks ----------
// 4 waves; wave w owns row tiles {w, w+4, w+8} plus column-group w of tile 12.
__global__ __launch_bounds__(256, 4) void sim_kernel(const _Float16* __restrict__ Apk,
                                                     const _Float16* __restrict__ Bpk,
                                                     const int* __restrict__ pm,
                                                     const float* __restrict__ ls,
                                                     float* __restrict__ out,
                                                     int* __restrict__ ctr) {
  __shared__ _Float16 Bsh[2 * CHUNK_H];     // 32 KB; epilogue scratch aliases this
  __shared__ int lastFlag;

  float* lpi = out + 1;
  float* lpt = out + 1 + 4096;

  const int j = blockIdx.x, i = blockIdx.y;
  const int tid = threadIdx.x;
  const int wave = tid >> 6, lane = tid & 63;
  const int r16 = lane & 15;
  const int lane8 = lane * 8;

  const _Float16* Ai = Apk + (size_t)i * 13 * 24 * 512;
  const _Float16* pA[4];
  pA[0] = Ai + (size_t)(wave)     * 24 * 512 + lane8;
  pA[1] = Ai + (size_t)(wave + 4) * 24 * 512 + lane8;
  pA[2] = Ai + (size_t)(wave + 8) * 24 * 512 + lane8;
  pA[3] = Ai + (size_t)12         * 24 * 512 + lane8;   // tile 12 (all waves)
  const _Float16* Bg = Bpk + (size_t)j * BJ_HALFS;

  // issue DMA for chunk 0 -> buf 0 (4 x 1024B per wave, contiguous)
#pragma unroll
  for (int r = 0; r < 4; ++r) {
    int u = wave * 4 + r;
    gl_lds16(Bg + u * 512 + lane8, Bsh + u * 512);
  }

  // A pipeline, depth 3
  half8 af[3][4];
#pragma unroll
  for (int d = 0; d < 3; ++d)
#pragma unroll
    for (int t = 0; t < 4; ++t)
      af[d][t] = *(const half8*)(pA[t] + d * 512);

  floatx4 acc[3][4];
  floatx4 acc12 = (floatx4){0.f, 0.f, 0.f, 0.f};
#pragma unroll
  for (int t = 0; t < 3; ++t)
#pragma unroll
    for (int cc = 0; cc < 4; ++cc)
      acc[t][cc] = (floatx4){0.f, 0.f, 0.f, 0.f};

#pragma unroll
  for (int c = 0; c < 6; ++c) {
    __syncthreads();                        // drains DMA chunk c; buf[(c+1)&1] is free
    if (c < 5) {                            // prefetch chunk c+1 during compute of c
#pragma unroll
      for (int r = 0; r < 4; ++r) {
        int u = wave * 4 + r;
        gl_lds16(Bg + (c + 1) * CHUNK_H + u * 512 + lane8,
                 Bsh + ((c + 1) & 1) * CHUNK_H + u * 512);
      }
    }
#pragma unroll
    for (int sc = 0; sc < 4; ++sc) {
      const int s = c * 4 + sc;
      half8 bfr[4];
#pragma unroll
      for (int cc = 0; cc < 4; ++cc) {
        int ct = (wave + cc) & 3;           // rotated: bfr[0] is this wave's own group
        bfr[cc] = *(const half8*)(Bsh + (c & 1) * CHUNK_H + (sc * 4 + ct) * 512 + lane8);
      }
      half8 a0 = af[s % 3][0], a1 = af[s % 3][1], a2 = af[s % 3][2], a3 = af[s % 3][3];
      if (s < 21) {                         // prefetch K-step s+3
#pragma unroll
        for (int t = 0; t < 4; ++t) af[s % 3][t] = *(const half8*)(pA[t] + (s + 3) * 512);
      }
#pragma unroll
      for (int cc = 0; cc < 4; ++cc) {
        acc[0][cc] = __builtin_amdgcn_mfma_f32_16x16x32_f16(a0, bfr[cc], acc[0][cc], 0, 0, 0);
        acc[1][cc] = __builtin_amdgcn_mfma_f32_16x16x32_f16(a1, bfr[cc], acc[1][cc], 0, 0, 0);
        acc[2][cc] = __builtin_amdgcn_mfma_f32_16x16x32_f16(a2, bfr[cc], acc[2][cc], 0, 0, 0);
      }
      acc12 = __builtin_amdgcn_mfma_f32_16x16x32_f16(a3, bfr[0], acc12, 0, 0, 0);
    }
  }

  // ---------------- epilogue ----------------
  const float sgl = ls[0];
  // mask depends on i only (reference broadcasts pm over i, not j)
  bool msk[4];
  int colc[4];
#pragma unroll
  for (int cc = 0; cc < 4; ++cc) {
    colc[cc] = ((wave + cc) & 3) * 16 + r16;
    msk[cc] = pm[i * 65 + 1 + colc[cc]] != 0;
  }

  // rows 0..191 row-max over valid m (each row counted by 16 r16-lanes)
  float rowsum = 0.f;
#pragma unroll
  for (int t = 0; t < 3; ++t) {
#pragma unroll
    for (int r = 0; r < 4; ++r) {
      float rm = -__builtin_inff();
#pragma unroll
      for (int cc = 0; cc < 4; ++cc) {
        float v = acc[t][cc][r] * sgl;
        rm = fmaxf(rm, msk[cc] ? -__builtin_inff() : v);
      }
#pragma unroll
      for (int off = 1; off < 16; off <<= 1)
        rm = fmaxf(rm, __shfl_xor(rm, off, 64));
      rowsum += rm;
    }
  }
#pragma unroll
  for (int off = 1; off < 64; off <<= 1) rowsum += __shfl_xor(rowsum, off, 64);

  // per-column max over rows 0..191 (unmasked, per reference max_n)
  float cmv[4];
#pragma unroll
  for (int cc = 0; cc < 4; ++cc) {
    float cm = -__builtin_inff();
#pragma unroll
    for (int t = 0; t < 3; ++t)
#pragma unroll
      for (int r = 0; r < 4; ++r)
        cm = fmaxf(cm, acc[t][cc][r] * sgl);
    cm = fmaxf(cm, __shfl_xor(cm, 16, 64));
    cm = fmaxf(cm, __shfl_xor(cm, 32, 64));
    cmv[cc] = cm;
  }

  __syncthreads();                          // all B reads done -> alias Bsh as scratch
  float* colmaxLDS = (float*)Bsh;           // [4][64]
  float* t12buf    = (float*)Bsh + 256;     // [4][64]
  float* wsumLDS   = (float*)Bsh + 512;     // [4]

  if (lane == 0) wsumLDS[wave] = rowsum;
  if (lane < 16) {
#pragma unroll
    for (int cc = 0; cc < 4; ++cc) colmaxLDS[wave * 64 + colc[cc]] = cmv[cc];
#pragma unroll
    for (int r = 0; r < 4; ++r) t12buf[r * 64 + wave * 16 + r16] = acc12[r] * sgl;
  }
  __syncthreads();

  if (tid < 64) {   // wave 0
    int col = tid;
    bool valid = pm[i * 65 + 1 + col] == 0;
    float t0 = t12buf[col], t1 = t12buf[64 + col], t2 = t12buf[128 + col], t3 = t12buf[192 + col];
    float v = fmaxf(fmaxf(colmaxLDS[col], colmaxLDS[64 + col]),
                    fmaxf(colmaxLDS[128 + col], colmaxLDS[192 + col]));
    v = fmaxf(v, fmaxf(fmaxf(t0, t1), fmaxf(t2, t3)));       // full col max (n=0..195)
    float contrib = valid ? v : 0.f;
    float cntv = valid ? 1.f : 0.f;
    float rs0 = valid ? t0 : -__builtin_inff();
    float rs1 = valid ? t1 : -__builtin_inff();
    float rs2 = valid ? t2 : -__builtin_inff();
    float rs3 = valid ? t3 : -__builtin_inff();
#pragma unroll
    for (int off = 1; off < 64; off <<= 1) {
      contrib += __shfl_xor(contrib, off, 64);
      cntv += __shfl_xor(cntv, off, 64);
      rs0 = fmaxf(rs0, __shfl_xor(rs0, off, 64));
      rs1 = fmaxf(rs1, __shfl_xor(rs1, off, 64));
      rs2 = fmaxf(rs2, __shfl_xor(rs2, off, 64));
      rs3 = fmaxf(rs3, __shfl_xor(rs3, off, 64));
    }
    if (tid == 0) {
      lpt[i * 64 + j] = contrib / cntv;
      float wtot = wsumLDS[0] + wsumLDS[1] + wsumLDS[2] + wsumLDS[3];
      lpi[i * 64 + j] = (wtot * 0.0625f + rs0 + rs1 + rs2 + rs3) / 196.f;
    }
  }

  // ---------------- fused CE: last block to finish computes the losses ----------------
  if (tid == 0) {
    __threadfence();                        // release this block's lpi/lpt
    int old = atomicAdd(ctr, 1);
    lastFlag = (old == 4095);
  }
  __syncthreads();
  if (lastFlag && tid < 64) {
    __threadfence();                        // acquire all blocks' lpi/lpt
    const int t = tid;
    float mx = -__builtin_inff();
    for (int jj = 0; jj < 64; ++jj) mx = fmaxf(mx, lpi[t * 64 + jj]);
    float se = 0.f;
    for (int jj = 0; jj < 64; ++jj) se += __expf(lpi[t * 64 + jj] - mx);
    float ci = (mx + __logf(se)) - lpi[t * 64 + t];

    float mx2 = -__builtin_inff();
    for (int jj = 0; jj < 64; ++jj) mx2 = fmaxf(mx2, lpt[t * 64 + jj]);
    float se2 = 0.f;
    for (int jj = 0; jj < 64; ++jj) se2 += __expf(lpt[t * 64 + jj] - mx2);
    float ct_ = (mx2 + __logf(se2)) - lpt[t * 64 + t];

    float v = ci + ct_;
#pragma unroll
    for (int off = 1; off < 64; off <<= 1) v += __shfl_xor(v, off, 64);
    if (t == 0) out[0] = 0.5f * v / 64.f;
    out[1 + 8192 + t] = (float)t;           // targets = arange(64)
  }
}

extern "C" void kernel_launch(void* const* d_in, const int* in_sizes, int n_in,
                              void* d_out, int out_size, void* d_ws, size_t ws_size,
                              hipStream_t stream) {
  const float* image = (const float*)d_in[0];   // (64,197,768) f32
  const float* text  = (const float*)d_in[1];   // (64,65,768) f32
  const int*   pm    = (const int*)d_in[2];     // (64,65) i32
  const float* ls    = (const float*)d_in[3];   // scalar
  float* out = (float*)d_out;

  _Float16* Apk = (_Float16*)d_ws;              // fragment-tiled image
  _Float16* Bpk = Apk + A_HALFS;                // fragment-tiled text
  int* ctr = (int*)(Bpk + T_HALFS);             // completion counter

  repack<<<(AUNITS + TUNITS) / 256, 256, 0, stream>>>(image, text, Apk, Bpk, ctr);

  dim3 grid(64, 64);   // x = j (fast): A_i reused by consecutive blocks
  sim_kernel<<<grid, 256, 0, stream>>>(Apk, Bpk, pm, ls, out, ctr);
}

// Round 6
// 203.830 us; speedup vs baseline: 2.0824x; 2.0824x over previous
//
#include <hip/hip_runtime.h>

typedef _Float16 half8 __attribute__((ext_vector_type(8)));
typedef float floatx4 __attribute__((ext_vector_type(4)));
typedef float float4v __attribute__((ext_vector_type(4)));

#define DIM   768
#define NROW  196
#define AUNITS (64 * 13 * 24 * 64)    // 16B units in A'' (fragment-tiled image)
#define TUNITS (64 * 4 * 24 * 64)     // 16B units in B'' (fragment-tiled text)
#define A_HALFS ((size_t)AUNITS * 8)
#define BJ_HALFS (24 * 4 * 64 * 8)    // 49152 halfs per j
#define CHUNK_H 8192                  // halfs per 4-K-step chunk (16 KB)

__device__ __forceinline__ void gl_lds16(const _Float16* g, _Float16* l) {
  __builtin_amdgcn_global_load_lds(
      (const __attribute__((address_space(1))) unsigned int*)g,
      (__attribute__((address_space(3))) unsigned int*)l, 16, 0, 0);
}

// ---------- repack: f32 -> f16 into MFMA-fragment-tiled layout ----------
// A''[i][tau][s][lane]{8}: lane l holds A_i[n=tau*16+(l&15)][d=s*32+(l>>4)*8..+7]
// B''[j][s][ct][lane]{8}:  lane l holds B_j[m=ct*16+(l&15)][d=s*32+(l>>4)*8..+7]
__global__ __launch_bounds__(256) void repack(const float* __restrict__ img,
                                              const float* __restrict__ txt,
                                              _Float16* __restrict__ Apk,
                                              _Float16* __restrict__ Bpk) {
  int gid = blockIdx.x * 256 + threadIdx.x;
  const float* src;
  _Float16* dst;
  if (gid < AUNITS) {
    int l = gid & 63, g = gid >> 6;
    int s = g % 24; g /= 24;
    int tau = g % 13; int i = g / 13;
    int n = tau * 16 + (l & 15); if (n > 195) n = 195;   // dup-pad rows 196..207
    src = img + (size_t)i * 197 * 768 + (size_t)(n + 1) * 768 + s * 32 + (l >> 4) * 8;
    dst = Apk + (size_t)gid * 8;
  } else {
    int u = gid - AUNITS;
    int l = u & 63, g = u >> 6;
    int ct = g & 3; g >>= 2;
    int s = g % 24; int j = g / 24;
    int m = ct * 16 + (l & 15);
    src = txt + (size_t)j * 65 * 768 + (size_t)(m + 1) * 768 + s * 32 + (l >> 4) * 8;
    dst = Bpk + (size_t)u * 8;
  }
  float4v v0 = *(const float4v*)src;
  float4v v1 = *(const float4v*)(src + 4);
  half8 h;
  h[0] = (_Float16)v0[0]; h[1] = (_Float16)v0[1]; h[2] = (_Float16)v0[2]; h[3] = (_Float16)v0[3];
  h[4] = (_Float16)v1[0]; h[5] = (_Float16)v1[1]; h[6] = (_Float16)v1[2]; h[7] = (_Float16)v1[3];
  *(half8*)dst = h;
}

// ---------- per-(i,j): A streamed via registers, B double-buffered DMA chunks ----------
// 4 waves; wave w owns row tiles {w, w+4, w+8} plus column-group w of tile 12.
__global__ __launch_bounds__(256, 3) void sim_kernel(const _Float16* __restrict__ Apk,
                                                     const _Float16* __restrict__ Bpk,
                                                     const int* __restrict__ pm,
                                                     const float* __restrict__ ls,
                                                     float* __restrict__ lpi,
                                                     float* __restrict__ lpt) {
  __shared__ _Float16 Bsh[2 * CHUNK_H];     // 32 KB; epilogue scratch aliases this

  const int j = blockIdx.x, i = blockIdx.y;
  const int tid = threadIdx.x;
  const int wave = tid >> 6, lane = tid & 63;
  const int r16 = lane & 15;
  const int lane8 = lane * 8;

  const _Float16* Ai = Apk + (size_t)i * 13 * 24 * 512;
  const _Float16* pA[4];
  pA[0] = Ai + (size_t)(wave)     * 24 * 512 + lane8;
  pA[1] = Ai + (size_t)(wave + 4) * 24 * 512 + lane8;
  pA[2] = Ai + (size_t)(wave + 8) * 24 * 512 + lane8;
  pA[3] = Ai + (size_t)12         * 24 * 512 + lane8;   // tile 12 (all waves)
  const _Float16* Bg = Bpk + (size_t)j * BJ_HALFS;

  // prime: DMA chunk 0 -> buf 0 (4 x 1024B contiguous per wave)
#pragma unroll
  for (int r = 0; r < 4; ++r) {
    int u = wave * 4 + r;
    gl_lds16(Bg + u * 512 + lane8, Bsh + u * 512);
  }

  // A pipeline, depth 2 (round-4-proven register budget)
  half8 af[2][4];
#pragma unroll
  for (int d = 0; d < 2; ++d)
#pragma unroll
    for (int t = 0; t < 4; ++t)
      af[d][t] = *(const half8*)(pA[t] + d * 512);

  floatx4 acc[3][4];
  floatx4 acc12 = (floatx4){0.f, 0.f, 0.f, 0.f};
#pragma unroll
  for (int t = 0; t < 3; ++t)
#pragma unroll
    for (int cc = 0; cc < 4; ++cc)
      acc[t][cc] = (floatx4){0.f, 0.f, 0.f, 0.f};

#pragma unroll
  for (int c = 0; c < 6; ++c) {
    __syncthreads();                        // drains chunk-c DMA; frees buf[(c+1)&1]
#pragma unroll
    for (int sc = 0; sc < 4; ++sc) {
      const int s = c * 4 + sc;
      // chunk c+1 DMA issued mid-chunk: AFTER step-0/1 A-prefetches (so earlier
      // A-waits don't force DMA completion), overlapping steps 2-3 + barrier.
      if (sc == 2 && c < 5) {
#pragma unroll
        for (int r = 0; r < 4; ++r) {
          int u = wave * 4 + r;
          gl_lds16(Bg + (c + 1) * CHUNK_H + u * 512 + lane8,
                   Bsh + ((c + 1) & 1) * CHUNK_H + u * 512);
        }
      }
      half8 bfr[4];
#pragma unroll
      for (int cc = 0; cc < 4; ++cc) {
        int ct = (wave + cc) & 3;           // rotated: bfr[0] is this wave's own group
        bfr[cc] = *(const half8*)(Bsh + (c & 1) * CHUNK_H + (sc * 4 + ct) * 512 + lane8);
      }
      half8 a0 = af[s & 1][0], a1 = af[s & 1][1], a2 = af[s & 1][2], a3 = af[s & 1][3];
      if (s < 22) {                         // prefetch K-step s+2
#pragma unroll
        for (int t = 0; t < 4; ++t) af[s & 1][t] = *(const half8*)(pA[t] + (s + 2) * 512);
      }
#pragma unroll
      for (int cc = 0; cc < 4; ++cc) {
        acc[0][cc] = __builtin_amdgcn_mfma_f32_16x16x32_f16(a0, bfr[cc], acc[0][cc], 0, 0, 0);
        acc[1][cc] = __builtin_amdgcn_mfma_f32_16x16x32_f16(a1, bfr[cc], acc[1][cc], 0, 0, 0);
        acc[2][cc] = __builtin_amdgcn_mfma_f32_16x16x32_f16(a2, bfr[cc], acc[2][cc], 0, 0, 0);
      }
      acc12 = __builtin_amdgcn_mfma_f32_16x16x32_f16(a3, bfr[0], acc12, 0, 0, 0);
    }
  }

  // ---------------- epilogue ----------------
  const float sgl = ls[0];
  // mask depends on i only (reference broadcasts pm over i, not j)
  bool msk[4];
  int colc[4];
#pragma unroll
  for (int cc = 0; cc < 4; ++cc) {
    colc[cc] = ((wave + cc) & 3) * 16 + r16;
    msk[cc] = pm[i * 65 + 1 + colc[cc]] != 0;
  }

  // rows 0..191 row-max over valid m (each row counted by 16 r16-lanes)
  float rowsum = 0.f;
#pragma unroll
  for (int t = 0; t < 3; ++t) {
#pragma unroll
    for (int r = 0; r < 4; ++r) {
      float rm = -__builtin_inff();
#pragma unroll
      for (int cc = 0; cc < 4; ++cc) {
        float v = acc[t][cc][r] * sgl;
        rm = fmaxf(rm, msk[cc] ? -__builtin_inff() : v);
      }
#pragma unroll
      for (int off = 1; off < 16; off <<= 1)
        rm = fmaxf(rm, __shfl_xor(rm, off, 64));
      rowsum += rm;
    }
  }
#pragma unroll
  for (int off = 1; off < 64; off <<= 1) rowsum += __shfl_xor(rowsum, off, 64);

  // per-column max over rows 0..191 (unmasked, per reference max_n)
  float cmv[4];
#pragma unroll
  for (int cc = 0; cc < 4; ++cc) {
    float cm = -__builtin_inff();
#pragma unroll
    for (int t = 0; t < 3; ++t)
#pragma unroll
      for (int r = 0; r < 4; ++r)
        cm = fmaxf(cm, acc[t][cc][r] * sgl);
    cm = fmaxf(cm, __shfl_xor(cm, 16, 64));
    cm = fmaxf(cm, __shfl_xor(cm, 32, 64));
    cmv[cc] = cm;
  }

  __syncthreads();                          // all B reads done -> alias Bsh as scratch
  float* colmaxLDS = (float*)Bsh;           // [4][64]
  float* t12buf    = (float*)Bsh + 256;     // [4][64]
  float* wsumLDS   = (float*)Bsh + 512;     // [4]

  if (lane == 0) wsumLDS[wave] = rowsum;
  if (lane < 16) {
#pragma unroll
    for (int cc = 0; cc < 4; ++cc) colmaxLDS[wave * 64 + colc[cc]] = cmv[cc];
#pragma unroll
    for (int r = 0; r < 4; ++r) t12buf[r * 64 + wave * 16 + r16] = acc12[r] * sgl;
  }
  __syncthreads();

  if (tid < 64) {   // wave 0
    int col = tid;
    bool valid = pm[i * 65 + 1 + col] == 0;
    float t0 = t12buf[col], t1 = t12buf[64 + col], t2 = t12buf[128 + col], t3 = t12buf[192 + col];
    float v = fmaxf(fmaxf(colmaxLDS[col], colmaxLDS[64 + col]),
                    fmaxf(colmaxLDS[128 + col], colmaxLDS[192 + col]));
    v = fmaxf(v, fmaxf(fmaxf(t0, t1), fmaxf(t2, t3)));       // full col max (n=0..195)
    float contrib = valid ? v : 0.f;
    float cntv = valid ? 1.f : 0.f;
    float rs0 = valid ? t0 : -__builtin_inff();
    float rs1 = valid ? t1 : -__builtin_inff();
    float rs2 = valid ? t2 : -__builtin_inff();
    float rs3 = valid ? t3 : -__builtin_inff();
#pragma unroll
    for (int off = 1; off < 64; off <<= 1) {
      contrib += __shfl_xor(contrib, off, 64);
      cntv += __shfl_xor(cntv, off, 64);
      rs0 = fmaxf(rs0, __shfl_xor(rs0, off, 64));
      rs1 = fmaxf(rs1, __shfl_xor(rs1, off, 64));
      rs2 = fmaxf(rs2, __shfl_xor(rs2, off, 64));
      rs3 = fmaxf(rs3, __shfl_xor(rs3, off, 64));
    }
    if (tid == 0) {
      lpt[i * 64 + j] = contrib / cntv;
      float wtot = wsumLDS[0] + wsumLDS[1] + wsumLDS[2] + wsumLDS[3];
      lpi[i * 64 + j] = (wtot * 0.0625f + rs0 + rs1 + rs2 + rs3) / 196.f;
    }
  }
}

// ---------------- CE losses + targets ----------------
// out layout: [0] loss | [1..4097) lpi | [4097..8193) lpt | [8193..8257) targets
__global__ __launch_bounds__(64) void ce_kernel(float* __restrict__ out) {
  const int t = threadIdx.x;
  const float* lpi = out + 1;
  const float* lpt = out + 1 + 4096;

  float mx = -__builtin_inff();
  for (int jj = 0; jj < 64; ++jj) mx = fmaxf(mx, lpi[t * 64 + jj]);
  float se = 0.f;
  for (int jj = 0; jj < 64; ++jj) se += __expf(lpi[t * 64 + jj] - mx);
  float ci = (mx + __logf(se)) - lpi[t * 64 + t];

  float mx2 = -__builtin_inff();
  for (int jj = 0; jj < 64; ++jj) mx2 = fmaxf(mx2, lpt[t * 64 + jj]);
  float se2 = 0.f;
  for (int jj = 0; jj < 64; ++jj) se2 += __expf(lpt[t * 64 + jj] - mx2);
  float ct_ = (mx2 + __logf(se2)) - lpt[t * 64 + t];

  float v = ci + ct_;
#pragma unroll
  for (int off = 1; off < 64; off <<= 1) v += __shfl_xor(v, off, 64);
  if (t == 0) out[0] = 0.5f * v / 64.f;
  out[1 + 8192 + t] = (float)t;   // targets = arange(64)
}

extern "C" void kernel_launch(void* const* d_in, const int* in_sizes, int n_in,
                              void* d_out, int out_size, void* d_ws, size_t ws_size,
                              hipStream_t stream) {
  const float* image = (const float*)d_in[0];   // (64,197,768) f32
  const float* text  = (const float*)d_in[1];   // (64,65,768) f32
  const int*   pm    = (const int*)d_in[2];     // (64,65) i32
  const float* ls    = (const float*)d_in[3];   // scalar
  float* out = (float*)d_out;

  _Float16* Apk = (_Float16*)d_ws;              // fragment-tiled image
  _Float16* Bpk = Apk + A_HALFS;                // fragment-tiled text

  repack<<<(AUNITS + TUNITS) / 256, 256, 0, stream>>>(image, text, Apk, Bpk);

  dim3 grid(64, 64);   // x = j (fast): A_i reused by consecutive blocks
  sim_kernel<<<grid, 256, 0, stream>>>(Apk, Bpk, pm, ls, out + 1, out + 1 + 4096);
  ce_kernel<<<1, 64, 0, stream>>>(out);
}